// Round 11
// baseline (149.860 us; speedup 1.0000x reference)
//
#include <hip/hip_runtime.h>
#include <hip/hip_bf16.h>

#define B_ 4
#define N_ 4096
#define C_ 256
#define D_ 32
#define LOG2E 1.44269504088896340736f
#define MFMA16 __builtin_amdgcn_mfma_f32_16x16x32_bf16

typedef __attribute__((ext_vector_type(8))) short short8;   // 8 x bf16 (4 VGPRs)
typedef __attribute__((ext_vector_type(4))) short short4v;  // 4 x bf16 (8 B)
typedef __attribute__((ext_vector_type(4))) float float4v;  // MFMA C/D frag

// cheap round-to-nearest-even fp32->bf16 (finite inputs only): 3 VALU ops
__device__ inline short f2bf_rne(float f) {
  unsigned u = __builtin_bit_cast(unsigned, f);
  u += 0x7FFFu + ((u >> 16) & 1u);
  return (short)(u >> 16);
}
__device__ inline float bf2f(short s) {
  unsigned u = ((unsigned)(unsigned short)s) << 16;
  return __builtin_bit_cast(float, u);
}
__device__ inline float fast_exp2(float x) { return __builtin_amdgcn_exp2f(x); }

// ---------------------------------------------------------------------------
// Kernel 1: fragment-linearized bf16 weights WtF. Frag f = nb*8+ks.
// Element (f, lane l, j) = W[k][n], n = nb*16+(l&15), k = ks*32+(l>>4)*8+j.
// log2(e) folded into Wq columns.
// ---------------------------------------------------------------------------
__global__ __launch_bounds__(256) void cast_w_kernel(
    const float* __restrict__ Wq, const float* __restrict__ Wk,
    const float* __restrict__ Wv, short* __restrict__ WtF) {
  int i  = blockIdx.x * 256 + threadIdx.x;  // 0..81919
  int j  = i & 7;
  int l  = (i >> 3) & 63;
  int ks = (i >> 9) & 7;
  int nb = i >> 12;
  int n  = nb * 16 + (l & 15);
  int k  = ks * 32 + ((l >> 4) << 3) + j;
  float v;
  if (n < 32)      v = Wq[k * 32 + n] * LOG2E;
  else if (n < 64) v = Wk[k * 32 + (n - 32)];
  else             v = Wv[k * 256 + (n - 64)];
  WtF[i] = f2bf_rne(v);
}

// ---------------------------------------------------------------------------
// Kernel 2: fused QKV projection v3 (unchanged from round 10).
// ---------------------------------------------------------------------------
__global__ __launch_bounds__(256, 2) void proj_kernel(
    const float* __restrict__ x, const short* __restrict__ WtF,
    const float* __restrict__ bq, const float* __restrict__ bk,
    const float* __restrict__ bv,
    short* __restrict__ qb, short* __restrict__ kF, short* __restrict__ vF) {
  int blk = blockIdx.x;
  int b  = blk >> 7;
  int r0 = (blk & 127) * 32;
  int t  = threadIdx.x;
  int w  = t >> 6;
  int l  = t & 63;
  int lc = l & 15;
  int q4 = l >> 4;

  __shared__ __align__(16) short sA[32][272];  // 17.4 KB
  __shared__ __align__(16) short sV[256][40];  // 20.5 KB  [ch][row]
  __shared__ __align__(16) short sK[32][36];   // 2.3 KB   [row][d]

  {
    const float* xb = x + (size_t)(b * N_ + r0) * C_;
#pragma unroll
    for (int ch = 0; ch < 8; ch++) {
      int f   = ch * 256 + t;
      int row = f >> 6;
      int col = (f & 63) * 4;
      float4v v = *(const float4v*)(xb + f * 4);
      short4v s;
      s[0] = f2bf_rne(v[0]); s[1] = f2bf_rne(v[1]);
      s[2] = f2bf_rne(v[2]); s[3] = f2bf_rne(v[3]);
      *(short4v*)(&sA[row][col]) = s;
    }
  }
  __syncthreads();

  float4v acc[10];  // [nbo*2 + rt]
#pragma unroll
  for (int i = 0; i < 10; i++) { acc[i][0] = 0.f; acc[i][1] = 0.f; acc[i][2] = 0.f; acc[i][3] = 0.f; }

  const short* wbase = WtF + w * 4096 + l * 8;  // frag(nbo,ks) at + nbo*16384 + ks*512

#define LOADW(B0, B1, B2, B3, B4, KS)                       \
  B0 = *(const short8*)(wbase + (KS) * 512 + 0 * 16384);    \
  B1 = *(const short8*)(wbase + (KS) * 512 + 1 * 16384);    \
  B2 = *(const short8*)(wbase + (KS) * 512 + 2 * 16384);    \
  B3 = *(const short8*)(wbase + (KS) * 512 + 3 * 16384);    \
  B4 = *(const short8*)(wbase + (KS) * 512 + 4 * 16384);

#define DO_MFMA(A0, A1, B0, B1, B2, B3, B4)                 \
  acc[0] = MFMA16(A0, B0, acc[0], 0, 0, 0);                 \
  acc[1] = MFMA16(A1, B0, acc[1], 0, 0, 0);                 \
  acc[2] = MFMA16(A0, B1, acc[2], 0, 0, 0);                 \
  acc[3] = MFMA16(A1, B1, acc[3], 0, 0, 0);                 \
  acc[4] = MFMA16(A0, B2, acc[4], 0, 0, 0);                 \
  acc[5] = MFMA16(A1, B2, acc[5], 0, 0, 0);                 \
  acc[6] = MFMA16(A0, B3, acc[6], 0, 0, 0);                 \
  acc[7] = MFMA16(A1, B3, acc[7], 0, 0, 0);                 \
  acc[8] = MFMA16(A0, B4, acc[8], 0, 0, 0);                 \
  acc[9] = MFMA16(A1, B4, acc[9], 0, 0, 0);

  short8 wA0, wA1, wA2, wA3, wA4, wB0, wB1, wB2, wB3, wB4;
  LOADW(wA0, wA1, wA2, wA3, wA4, 0)
#pragma unroll
  for (int kk = 0; kk < 8; kk += 2) {
    short8 a00 = *(const short8*)(&sA[lc][kk * 32 + q4 * 8]);
    short8 a01 = *(const short8*)(&sA[16 + lc][kk * 32 + q4 * 8]);
    LOADW(wB0, wB1, wB2, wB3, wB4, kk + 1)
    DO_MFMA(a00, a01, wA0, wA1, wA2, wA3, wA4)
    short8 a10 = *(const short8*)(&sA[lc][(kk + 1) * 32 + q4 * 8]);
    short8 a11 = *(const short8*)(&sA[16 + lc][(kk + 1) * 32 + q4 * 8]);
    LOADW(wA0, wA1, wA2, wA3, wA4, kk + 2)  // kk+2==8: harmless in-ws overread
    DO_MFMA(a10, a11, wB0, wB1, wB2, wB3, wB4)
  }
#undef LOADW
#undef DO_MFMA

  // epilogue: bias + cast; q scatter (tiny), k -> sK, v -> sV (b64 packed)
  {
    float bias0 = (w < 2) ? bq[w * 16 + lc] * LOG2E : bk[(w - 2) * 16 + lc];
#pragma unroll
    for (int rt = 0; rt < 2; rt++) {
      if (w < 2) {
#pragma unroll
        for (int r = 0; r < 4; r++) {
          int row = rt * 16 + q4 * 4 + r;
          qb[(size_t)(b * N_ + r0 + row) * D_ + w * 16 + lc] =
              f2bf_rne(acc[rt][r] + bias0);
        }
      } else {
#pragma unroll
        for (int r = 0; r < 4; r++) {
          int row = rt * 16 + q4 * 4 + r;
          sK[row][(w - 2) * 16 + lc] = f2bf_rne(acc[rt][r] + bias0);
        }
      }
    }
#pragma unroll
    for (int nbo = 1; nbo < 5; nbo++) {
      float bias = bv[(nbo - 1) * 64 + w * 16 + lc];
#pragma unroll
      for (int rt = 0; rt < 2; rt++) {
        float4v a = acc[nbo * 2 + rt];
        short4v pk;
        pk[0] = f2bf_rne(a[0] + bias); pk[1] = f2bf_rne(a[1] + bias);
        pk[2] = f2bf_rne(a[2] + bias); pk[3] = f2bf_rne(a[3] + bias);
        *(short4v*)(&sV[(nbo - 1) * 64 + w * 16 + lc][rt * 16 + q4 * 4]) = pk;
      }
    }
  }
  __syncthreads();

  int kt  = r0 >> 6;          // kv-tile these 32 rows belong to
  int ks0 = (r0 >> 5) & 1;    // which 32-kv half of the tile

  // vF writer: thread t writes 64 B CONTIGUOUS at tb2 + t*64B.
  {
    size_t tb2 = ((size_t)(b * 64 + kt) * 32 + ks0 * 16) * 512;
    int cb = t >> 4;
#pragma unroll
    for (int k = 0; k < 4; k++) {
      int p = (t & 15) * 4 + k;
      int j = p >> 4, i = p & 15;
      short8 vv = *(const short8*)(&sV[cb * 16 + i][j * 8]);
      *(short8*)(vF + tb2 + (size_t)t * 32 + k * 8) = vv;
    }
  }
  // kF writer: threads 0..127 write 16 B contiguous each.
  if (t < 128) {
    int fr = t >> 6, ll = t & 63;
    int kv = fr * 16 + (ll & 15), dg = ll >> 4;
    size_t tbk = ((size_t)(b * 64 + kt) * 4 + ks0 * 2) * 512;
    short8 kv8 = *(const short8*)(&sK[kv][dg * 8]);
    *(short8*)(kF + tbk + (size_t)t * 8) = kv8;
  }
}

// ---------------------------------------------------------------------------
// Kernel 3: flash, CHANNEL-split (no merge kernel). 512 blocks x 512 thr.
// Block = (b, qt 64 q-rows, ch-half hc of 128). Full 4096-kv loop (64 tiles).
// QK duplicated across the 2 hc blocks (+1 GF total; l computed identically
// in both -> consistent normalization, NO cross-block communication).
// Per tile (R7 wave layout): waves 0-3 QK rowtile rq + PV(kh=0); waves 4-7
// PV(kh=1). Wave owns 32 ch of the 128. End: 2-barrier in-block fp32 LDS
// merge of kh-pair O accs (reuses sP), then fused epilogue
// out = gamma*O/l + x written directly.
// ---------------------------------------------------------------------------
__global__ __launch_bounds__(512, 4) void flash_kernel(
    const short* __restrict__ qb, const short* __restrict__ kF,
    const short* __restrict__ vF, const float* __restrict__ xin,
    const float* __restrict__ gptr, float* __restrict__ out) {
  int blk = blockIdx.x;
  int b  = blk & 3;            // XCD (blk%8) <-> (b,hc): V-slice L2-resident
  int hc = (blk >> 2) & 1;
  int qt = blk >> 3;
  int r0 = qt * 64;
  int t  = threadIdx.x;
  int w  = t >> 6;
  int l  = t & 63;
  int lc = l & 15;
  int q4 = l >> 4;
  int rq = w & 3;
  int cq = w & 3;
  int khs = (w >> 2) * 32;     // kv-half offset within tile for PV
  bool qkw = (w < 4);

  __shared__ __align__(16) short sP[2][64][72];  // 18.4 KB, [q][kv]
  __shared__ float sL[64];

  // Q as B-frag (n=q, k=d); log2e pre-folded
  short8 qf = *(const short8*)(qb + (size_t)(b * N_ + r0 + rq * 16 + lc) * D_ + q4 * 8);

  const short* kbp = kF + ((size_t)(b * 64) * 4) * 512 + l * 8;
  const short* vbp = vF + ((size_t)(b * 64) * 32 + (w >> 2) * 16 + hc * 8 + cq * 2) * 512 + l * 8;

  short8 kC0, kC1, kC2, kC3;   // K A-frags (current tile)
  short8 vX0, vX1, vY0, vY1;   // V B-frags [cbo], double-buffered

  kC0 = *(const short8*)(kbp + 0);
  kC1 = *(const short8*)(kbp + 512);
  kC2 = *(const short8*)(kbp + 1024);
  kC3 = *(const short8*)(kbp + 1536);
  vX0 = *(const short8*)(vbp + 0);
  vX1 = *(const short8*)(vbp + 512);

  float4v O[8];  // [rt*2 + cbo]: 64 q x 32 ch (this wave's kh contribution)
#pragma unroll
  for (int i = 0; i < 8; i++) { O[i][0] = 0.f; O[i][1] = 0.f; O[i][2] = 0.f; O[i][3] = 0.f; }
  float l_part = 0.f;

#define K_RELOAD(TI)                                                           \
  { size_t o_ = (size_t)(TI) * 2048;                                           \
    kC0 = *(const short8*)(kbp + o_);                                          \
    kC1 = *(const short8*)(kbp + o_ + 512);                                    \
    kC2 = *(const short8*)(kbp + o_ + 1024);                                   \
    kC3 = *(const short8*)(kbp + o_ + 1536); }

#define QK_STEP(SPB, VALID)                                                    \
  { float4v z; z[0] = 0.f; z[1] = 0.f; z[2] = 0.f; z[3] = 0.f;                 \
    float4v S0 = MFMA16(kC0, qf, z, 0, 0, 0);                                  \
    float4v S1 = MFMA16(kC1, qf, z, 0, 0, 0);                                  \
    float4v S2 = MFMA16(kC2, qf, z, 0, 0, 0);                                  \
    float4v S3 = MFMA16(kC3, qf, z, 0, 0, 0);                                  \
    short* rowp = &sP[SPB][rq * 16 + lc][q4 * 4];                              \
    float ts = 0.f;                                                            \
    { float p0 = fast_exp2(S0[0]), p1 = fast_exp2(S0[1]);                      \
      float p2 = fast_exp2(S0[2]), p3 = fast_exp2(S0[3]);                      \
      ts += (p0 + p1) + (p2 + p3);                                             \
      short4v pk; pk[0] = f2bf_rne(p0); pk[1] = f2bf_rne(p1);                  \
      pk[2] = f2bf_rne(p2); pk[3] = f2bf_rne(p3);                              \
      *(short4v*)(rowp + 0) = pk; }                                            \
    { float p0 = fast_exp2(S1[0]), p1 = fast_exp2(S1[1]);                      \
      float p2 = fast_exp2(S1[2]), p3 = fast_exp2(S1[3]);                      \
      ts += (p0 + p1) + (p2 + p3);                                             \
      short4v pk; pk[0] = f2bf_rne(p0); pk[1] = f2bf_rne(p1);                  \
      pk[2] = f2bf_rne(p2); pk[3] = f2bf_rne(p3);                              \
      *(short4v*)(rowp + 16) = pk; }                                           \
    { float p0 = fast_exp2(S2[0]), p1 = fast_exp2(S2[1]);                      \
      float p2 = fast_exp2(S2[2]), p3 = fast_exp2(S2[3]);                      \
      ts += (p0 + p1) + (p2 + p3);                                             \
      short4v pk; pk[0] = f2bf_rne(p0); pk[1] = f2bf_rne(p1);                  \
      pk[2] = f2bf_rne(p2); pk[3] = f2bf_rne(p3);                              \
      *(short4v*)(rowp + 32) = pk; }                                           \
    { float p0 = fast_exp2(S3[0]), p1 = fast_exp2(S3[1]);                      \
      float p2 = fast_exp2(S3[2]), p3 = fast_exp2(S3[3]);                      \
      ts += (p0 + p1) + (p2 + p3);                                             \
      short4v pk; pk[0] = f2bf_rne(p0); pk[1] = f2bf_rne(p1);                  \
      pk[2] = f2bf_rne(p2); pk[3] = f2bf_rne(p3);                              \
      *(short4v*)(rowp + 48) = pk; }                                           \
    if (VALID) l_part += ts; }

#define PV_STEP(SPB, V0, V1)                                                   \
  { _Pragma("unroll")                                                          \
    for (int rt = 0; rt < 4; rt++) {                                           \
      short8 pf = *(const short8*)(&sP[SPB][rt * 16 + lc][khs + q4 * 8]);      \
      O[rt * 2 + 0] = MFMA16(pf, V0, O[rt * 2 + 0], 0, 0, 0);                  \
      O[rt * 2 + 1] = MFMA16(pf, V1, O[rt * 2 + 1], 0, 0, 0);                  \
    } }

  if (qkw) {
    QK_STEP(0, true)
    K_RELOAD(1)
  }
  __syncthreads();

  for (int ti = 0; ti < 64; ti += 2) {
    int n1 = ti + 1;
    int n2 = (ti + 2 < 64) ? ti + 2 : 63;
    bool v2 = (ti + 2 < 64);
    int n3 = (ti + 3 < 64) ? ti + 3 : 63;

    // ---- half A: QK(n1)->sP1 || PV(ti) from sP0 ----
    { size_t vo = (size_t)n1 * 16384;
      vY0 = *(const short8*)(vbp + vo);
      vY1 = *(const short8*)(vbp + vo + 512); }
    if (qkw) {
      QK_STEP(1, true)
      K_RELOAD(n2)
    }
    PV_STEP(0, vX0, vX1)
    __syncthreads();

    // ---- half B: QK(n2)->sP0 || PV(n1) from sP1 ----
    { size_t vo = (size_t)n2 * 16384;
      vX0 = *(const short8*)(vbp + vo);
      vX1 = *(const short8*)(vbp + vo + 512); }
    if (qkw) {
      QK_STEP(0, v2)   // clamped tail recompute; l not double-counted
      K_RELOAD(n3)
    }
    PV_STEP(1, vY0, vY1)
    __syncthreads();
  }
#undef K_RELOAD
#undef QK_STEP
#undef PV_STEP

  // ---- l reduce (QK waves; full-kv denominator) ----
  if (qkw) {
    float l_tot = l_part + __shfl_xor(l_part, 16, 64);
    l_tot += __shfl_xor(l_tot, 32, 64);
    if (q4 == 0) sL[rq * 16 + lc] = l_tot;
  }

  // ---- in-block kh-pair O merge (fp32, via sP reused as sM, 16 KB) ----
  float4v* sM = (float4v*)(&sP[0][0][0]);   // [cq*4 + j][64 lanes]
  if (!qkw) {
#pragma unroll
    for (int j = 0; j < 4; j++) sM[(cq * 4 + j) * 64 + l] = O[j];
  }
  __syncthreads();
  if (qkw) {
#pragma unroll
    for (int j = 0; j < 4; j++) {
      float4v m = sM[(cq * 4 + j) * 64 + l];
      O[j][0] += m[0]; O[j][1] += m[1]; O[j][2] += m[2]; O[j][3] += m[3];
    }
#pragma unroll
    for (int j = 0; j < 4; j++) sM[(cq * 4 + j) * 64 + l] = O[4 + j];
  }
  __syncthreads();
  if (!qkw) {
#pragma unroll
    for (int j = 0; j < 4; j++) {
      float4v m = sM[(cq * 4 + j) * 64 + l];
      O[4 + j][0] += m[0]; O[4 + j][1] += m[1];
      O[4 + j][2] += m[2]; O[4 + j][3] += m[3];
    }
  }

  // ---- fused epilogue: waves 0-3 write rt{0,1}, waves 4-7 write rt{2,3} ----
  float g = *gptr;
  int rtb = qkw ? 0 : 2;
  int chb = hc * 128 + cq * 32;
#pragma unroll
  for (int jrt = 0; jrt < 2; jrt++) {
    int rt = rtb + jrt;
#pragma unroll
    for (int r = 0; r < 4; r++) {
      int q = rt * 16 + q4 * 4 + r;
      float linv = __builtin_amdgcn_rcpf(sL[q]);
      size_t base = (size_t)(b * N_ + r0 + q) * C_ + chb;
#pragma unroll
      for (int cbo = 0; cbo < 2; cbo++) {
        int a = jrt * 2 + cbo + (qkw ? 0 : 4);
        size_t idx = base + cbo * 16 + lc;
        out[idx] = g * (O[a][r] * linv) + xin[idx];
      }
    }
  }
}

// ---------------------------------------------------------------------------
extern "C" void kernel_launch(void* const* d_in, const int* in_sizes, int n_in,
                              void* d_out, int out_size, void* d_ws, size_t ws_size,
                              hipStream_t stream) {
  const float* x     = (const float*)d_in[0];
  const float* Wq    = (const float*)d_in[1];
  const float* bq    = (const float*)d_in[2];
  const float* Wk    = (const float*)d_in[3];
  const float* bk    = (const float*)d_in[4];
  const float* Wv    = (const float*)d_in[5];
  const float* bv    = (const float*)d_in[6];
  const float* gamma = (const float*)d_in[7];
  float* out = (float*)d_out;

  char* ws = (char*)d_ws;
  short* qb   = (short*)ws;                   // 1 MB   row-major [N][32]
  short* kF   = (short*)(ws + (1u << 20));    // 1 MB   fragment-linear
  short* vF   = (short*)(ws + (2u << 20));    // 8 MB   fragment-linear
  short* WtF  = (short*)(ws + (10u << 20));   // 160 KB fragment-linear

  hipLaunchKernelGGL(cast_w_kernel, dim3(320), dim3(256), 0, stream, Wq, Wk, Wv, WtF);
  hipLaunchKernelGGL(proj_kernel,   dim3(512), dim3(256), 0, stream, x, WtF, bq, bk, bv, qb, kF, vF);
  hipLaunchKernelGGL(flash_kernel,  dim3(512), dim3(512), 0, stream, qb, kF, vF, x, gamma, out);
}